// Round 6
// baseline (220.811 us; speedup 1.0000x reference)
//
#include <hip/hip_runtime.h>

// MemoryProjection: x_t = A x_{t-1} + in_t * Bd, out = all states (2048,8,64,64) fp32.
// Chunked: out[j*64+tau] = A^(tau+1) x0_j + sum_{k<=tau} (A^(tau-k) Bd) in[j*64+k]
// => one fp16 MFMA GEMM: C[m=(j,q)][nn=(tau,n)] = R16[m][:] . W16[nn][:], K=256
//    R16 = [in(64) | x0h(64) | x0h(64) | x0l(64)], W16 = [Kmat | Ph | Pl | Ph]
// kA: P[tau]=A^(tau+1) chains via f16 h/l-compensated MFMA matmuls (1 transpose/block)
// kB: blocks 0..127 input transpose->R16; 128..191 W16 Kmat; 192..319 fused conv+scan
// kC: 128x128 MFMA GEMM. LDS-FREE main loop: fragments loaded straight from L2
//     (R16 tile reused by 32 blocks, W16 by 128, XCD-local via swizzle) with
//     named-register double buffering; no barriers until the staged nt-store epilogue.
//     Rationale: previous LDS staging pushed 512KB/block through the per-CU LDS
//     pipe (~30-40us/CU) -- same order as the 40us HBM write floor.

typedef _Float16 f16;
typedef __attribute__((ext_vector_type(8))) _Float16 f16x8;
typedef __attribute__((ext_vector_type(4))) float f32x4;

// ---------------- kA: powers via h/l MFMA + W16 Ph/Pl + Kv + A64 ----------------
__global__ __launch_bounds__(1024) void kA_pow(
    const float* __restrict__ A, const float* __restrict__ Bm,
    float* __restrict__ A64, float* __restrict__ Kv, f16* __restrict__ W16)
{
  __shared__ __align__(16) f16 Ah[64][72],  Al[64][72];   // A row-major h/l
  __shared__ __align__(16) f16 B0h[64][72], B0l[64][72];  // ping
  __shared__ __align__(16) f16 B1h[64][72], B1l[64][72];  // pong
  __shared__ __align__(16) f16 Y8h[64][72], Y8l[64][72];  // (A^8)^T capture
  __shared__ __align__(16) f16 Ybh[64][72], Ybl[64][72];  // (A^b)^T capture

  int tau = blockIdx.x;
  int e = tau + 1;
  int a = e >> 3, b = e & 7;
  int t = threadIdx.x;
  int wave = t >> 6, lane = t & 63;
  int tn = wave >> 2, tm = wave & 3;       // 4x4 grid of 16x16 tiles
  int kg = lane >> 4, fr = lane & 15;

  // D = P * Q^T (both row-major [row][k]), h/l compensated; D split to h/l.
  auto mm = [&](f16 (*Ph)[72], f16 (*Pl)[72], f16 (*Qh)[72], f16 (*Ql)[72],
                f16 (*Dh)[72], f16 (*Dl)[72]) {
    f32x4 acc = {};
    #pragma unroll
    for (int kk = 0; kk < 2; ++kk) {
      f16x8 ah = *(const f16x8*)&Ph[tn * 16 + fr][kk * 32 + kg * 8];
      f16x8 al = *(const f16x8*)&Pl[tn * 16 + fr][kk * 32 + kg * 8];
      f16x8 bh = *(const f16x8*)&Qh[tm * 16 + fr][kk * 32 + kg * 8];
      f16x8 bl = *(const f16x8*)&Ql[tm * 16 + fr][kk * 32 + kg * 8];
      acc = __builtin_amdgcn_mfma_f32_16x16x32_f16(ah, bh, acc, 0, 0, 0);
      acc = __builtin_amdgcn_mfma_f32_16x16x32_f16(ah, bl, acc, 0, 0, 0);
      acc = __builtin_amdgcn_mfma_f32_16x16x32_f16(al, bh, acc, 0, 0, 0);
    }
    #pragma unroll
    for (int r = 0; r < 4; ++r) {
      float v = acc[r];
      f16 h = (f16)v, l = (f16)(v - (float)h);
      Dh[tn * 16 + kg * 4 + r][tm * 16 + fr] = h;
      Dl[tn * 16 + kg * 4 + r][tm * 16 + fr] = l;
    }
    __syncthreads();
  };
  auto cpy2 = [&](f16 (*Sh)[72], f16 (*Sl)[72], f16 (*Dh)[72], f16 (*Dl)[72]) {
    const unsigned* sh = (const unsigned*)Sh; unsigned* dh = (unsigned*)Dh;
    const unsigned* sl = (const unsigned*)Sl; unsigned* dl = (unsigned*)Dl;
    for (int idx = t; idx < 2304; idx += 1024) { dh[idx] = sh[idx]; dl[idx] = sl[idx]; }
  };

  // init: Ah/Al = h/l(A) row-major; ping = h/l(A^T) = Y_1
  for (int idx = t; idx < 4096; idx += 1024) {
    float v = A[idx];
    int r = idx >> 6, c2 = idx & 63;
    f16 h = (f16)v, l = (f16)(v - (float)h);
    Ah[r][c2] = h;  Al[r][c2] = l;
    B0h[c2][r] = h; B0l[c2][r] = l;
  }
  __syncthreads();

  f16 (*curH)[72] = B0h; f16 (*curL)[72] = B0l;
  f16 (*othH)[72] = B1h; f16 (*othL)[72] = B1l;
  auto swp = [&]() {
    f16 (*tH)[72] = curH; curH = othH; othH = tH;
    f16 (*tL)[72] = curL; curL = othL; othL = tL;
  };

  if (b == 1) cpy2(curH, curL, Ybh, Ybl);

  // lo chain (transposed space): Y_{i+1} = mfma(Y_i, A_rm)
  int loMax = (a >= 1) ? 8 : b;
  for (int i = 2; i <= loMax; ++i) {
    mm(curH, curL, Ah, Al, othH, othL);
    swp();
    if (i == b) cpy2(curH, curL, Ybh, Ybl);
    if (i == 8) cpy2(curH, curL, Y8h, Y8l);
  }

  f16 (*Rh)[72]; f16 (*Rl)[72]; bool tr;
  if (a == 0) {
    Rh = curH; Rl = curL; tr = true;                // result = Y_b^T
  } else {
    // H_1 = A^8 = transpose(Y_8) (Y_8 currently in cur)
    for (int idx = t; idx < 4096; idx += 1024) {
      int i = idx >> 6, j = idx & 63;
      othH[i][j] = curH[j][i];
      othL[i][j] = curL[j][i];
    }
    swp();
    __syncthreads();
    for (int a2 = 2; a2 <= a; ++a2) {               // H_{a+1} = mfma(H_a, Y8)
      mm(curH, curL, Y8h, Y8l, othH, othL);
      swp();
    }
    if (b >= 1) {                                   // P = mfma(H_a, Y_b)
      mm(curH, curL, Ybh, Ybl, othH, othL);
      swp();
    }
    Rh = curH; Rl = curL; tr = false;
  }

  // epilogue: W16 rows [64..128)=Ph, [128..192)=Pl, [192..256)=Ph; A64; Kv
  for (int idx = t; idx < 4096; idx += 1024) {
    int wn = idx >> 6, m = idx & 63;
    f16 h = tr ? Rh[m][wn] : Rh[wn][m];
    f16 l = tr ? Rl[m][wn] : Rl[wn][m];
    f16* wrow = W16 + ((size_t)(tau * 64 + wn)) * 256;
    wrow[64 + m] = h; wrow[128 + m] = l; wrow[192 + m] = h;
    if (tau == 63) A64[idx] = (float)h + (float)l;
  }
  if (t < 64) {
    float s = 0.f;
    #pragma unroll 8
    for (int m = 0; m < 64; ++m) {
      float pv = tr ? ((float)Rh[m][t] + (float)Rl[m][t])
                    : ((float)Rh[t][m] + (float)Rl[t][m]);
      s += pv * Bm[m];
    }
    if (tau < 63) Kv[(tau + 1) * 64 + t] = s;
    else          Kv[t] = Bm[t];
  }
}

// ---------------- kB: transpose | Kmat | fused conv+scan ----------------
__global__ __launch_bounds__(256) void kB_prep(
    const float* __restrict__ inp, const float* __restrict__ Kv,
    const float* __restrict__ A64,
    f16* __restrict__ R16, f16* __restrict__ W16)
{
  __shared__ __align__(16) float sm[64 * 132];
  int t = threadIdx.x;
  int b = blockIdx.x;
  if (b < 128) {
    // input transpose: R16[(j*512+q)][k] = fp16(in[j*64+k][q])
    float (*tile)[132] = (float (*)[132])sm;
    int j = b >> 2, qb = (b & 3) * 128;
    {
      int k = t >> 2, sg = (t & 3) * 32;
      const float* src = inp + j * 32768 + k * 512 + qb + sg;
      #pragma unroll
      for (int i = 0; i < 32; i += 4)
        *(f32x4*)(&tile[k][sg + i]) = *(const f32x4*)(src + i);
    }
    __syncthreads();
    int q = t >> 1, kh = (t & 1) * 32;
    f16 tmp[32];
    #pragma unroll
    for (int kk = 0; kk < 32; ++kk)
      tmp[kk] = (f16)tile[kh + kk][q];
    f16* dst = R16 + ((size_t)(j * 512 + qb + q)) * 256 + kh;
    #pragma unroll
    for (int v = 0; v < 4; ++v)
      *(f16x8*)(dst + v * 8) = *(const f16x8*)(&tmp[v * 8]);
  } else if (b < 192) {
    // Kmat rows: W16[(tau*64+wn)][k] = (k<=tau) ? Kv[tau-k][wn] : 0
    int tau = b - 128;
    float* KT = sm;
    for (int idx = t; idx < 4096; idx += 256) KT[idx] = Kv[idx];
    __syncthreads();
    int wn = t & 63, kq = t >> 6;
    f16* wrow = W16 + ((size_t)(tau * 64 + wn)) * 256 + kq * 16;
    #pragma unroll
    for (int ki = 0; ki < 16; ++ki) {
      int k = kq * 16 + ki;
      wrow[ki] = (f16)((k <= tau) ? KT[(tau - k) * 64 + wn] : 0.0f);
    }
  } else {
    // fused conv+scan: one wave per q column
    int wv = t >> 6, L = t & 63;
    int q = (b - 192) * 4 + wv;
    float ar[64], kvr[64];
    #pragma unroll
    for (int m = 0; m < 64; m += 4) {
      f32x4 v4 = *(const f32x4*)(A64 + L * 64 + m);
      ar[m] = v4.x; ar[m + 1] = v4.y; ar[m + 2] = v4.z; ar[m + 3] = v4.w;
    }
    #pragma unroll
    for (int k = 0; k < 64; ++k) kvr[k] = Kv[(63 - k) * 64 + L];
    float x = 0.f;
    float v = inp[(size_t)L * 512 + q];
    for (int j = 0; j < 32; ++j) {
      float vn = (j < 31) ? inp[(size_t)((j + 1) * 64 + L) * 512 + q] : 0.f;
      f16 hh = (f16)x, ll = (f16)(x - (float)hh);
      f16* row = R16 + ((size_t)(j * 512 + q)) * 256;
      row[64 + L] = hh; row[128 + L] = hh; row[192 + L] = ll;
      float a0 = 0.f, a1 = 0.f, c0 = 0.f, c1 = 0.f;
      #pragma unroll
      for (int m = 0; m < 64; m += 2) {
        a0 += ar[m]     * __shfl(x, m);
        a1 += ar[m + 1] * __shfl(x, m + 1);
        c0 += kvr[m]    * __shfl(v, m);
        c1 += kvr[m + 1]* __shfl(v, m + 1);
      }
      x = (a0 + a1) + (c0 + c1);
      v = vn;
    }
  }
}

// ---------------- kC: C[16384 x 4096] = R16 @ W16^T, LDS-free main loop ----------------
__global__ __launch_bounds__(256, 3) void kC_gemm(
    const f16* __restrict__ R16, const f16* __restrict__ W16,
    float* __restrict__ out)
{
  __shared__ __align__(16) float stg[128][68];   // epilogue staging only (34.8 KB)
  int wg = blockIdx.x;
  int swz = (wg & 7) * 512 + (wg >> 3);     // XCD-contiguous mt ranges
  int mt = swz >> 5, nt = swz & 31;
  int t = threadIdx.x, wave = t >> 6, lane = t & 63;
  int wr = wave >> 1, wc = wave & 1;
  int kg = lane >> 4, fr = lane & 15;

  // fragment base pointers: af[i](g) = R16[mt*128 + wr*64 + i*16 + fr][g*32 + kg*8]
  const f16* Abase = R16 + ((size_t)(mt * 128 + wr * 64 + fr)) * 256 + kg * 8;
  const f16* Bbase = W16 + ((size_t)(nt * 128 + wc * 64 + fr)) * 256 + kg * 8;

  f32x4 acc[4][4] = {};
  f16x8 aC[4], bC[4], aN[4], bN[4];

  auto LD = [&](int g, f16x8* av, f16x8* bv) {
    #pragma unroll
    for (int i = 0; i < 4; ++i) {
      av[i] = *(const f16x8*)(Abase + i * 16 * 256 + g * 32);
      bv[i] = *(const f16x8*)(Bbase + i * 16 * 256 + g * 32);
    }
  };
  auto MM = [&](const f16x8* av, const f16x8* bv) {
    #pragma unroll
    for (int mi = 0; mi < 4; ++mi)
      #pragma unroll
      for (int ni = 0; ni < 4; ++ni)
        acc[mi][ni] = __builtin_amdgcn_mfma_f32_16x16x32_f16(
            av[mi], bv[ni], acc[mi][ni], 0, 0, 0);
  };

  LD(0, aC, bC);
  #pragma unroll
  for (int h = 0; h < 4; ++h) {
    LD(2 * h + 1, aN, bN);        // prefetch odd group
    MM(aC, bC);
    if (h < 3) LD(2 * h + 2, aC, bC);  // prefetch next even group
    MM(aN, bN);
  }

  // epilogue: per tau-half, stage 128x64 f32 tile in LDS, nt-write 32KB contiguous
  int j = mt >> 2, q0 = (mt & 3) * 128;
  #pragma unroll
  for (int half = 0; half < 2; ++half) {
    __syncthreads();
    if (wc == half) {
      #pragma unroll
      for (int mi = 0; mi < 4; ++mi)
        #pragma unroll
        for (int ni = 0; ni < 4; ++ni)
          #pragma unroll
          for (int r = 0; r < 4; ++r)
            stg[wr * 64 + mi * 16 + kg * 4 + r][ni * 16 + fr] = acc[mi][ni][r];
    }
    __syncthreads();
    int tau_g = nt * 2 + half;
    float* obase = out + (size_t)j * 2097152 + (size_t)tau_g * 32768 + (size_t)q0 * 64;
    #pragma unroll
    for (int it = 0; it < 8; ++it) {
      int fi = it * 1024 + t * 4;
      int rr = fi >> 6, cc = fi & 63;
      __builtin_nontemporal_store(*(const f32x4*)(&stg[rr][cc]),
                                  (f32x4*)(obase + fi));
    }
  }
}

extern "C" void kernel_launch(void* const* d_in, const int* in_sizes, int n_in,
                              void* d_out, int out_size, void* d_ws, size_t ws_size,
                              hipStream_t stream)
{
  (void)in_sizes; (void)n_in; (void)out_size; (void)ws_size;
  const float* inp = (const float*)d_in[0];   // (2048, 8, 64) fp32
  const float* A   = (const float*)d_in[1];   // (64, 64) fp32
  const float* Bm  = (const float*)d_in[2];   // (64, 1) fp32
  float* out = (float*)d_out;                 // (2048, 8, 64, 64) fp32

  float* ws = (float*)d_ws;
  float* A64 = ws;                            // 4096 f32   (16 KB)
  float* Kv  = ws + 4096;                     // 4096 f32   (16 KB)
  f16*  W16  = (f16*)(ws + 8192);             // 4096*256 f16 (2 MB)
  f16*  R16  = (f16*)((char*)d_ws + 2129920); // 16384*256 f16 (8 MB)

  hipLaunchKernelGGL(kA_pow,  dim3(64),   dim3(1024), 0, stream, A, Bm, A64, Kv, W16);
  hipLaunchKernelGGL(kB_prep, dim3(320),  dim3(256),  0, stream, inp, Kv, A64, R16, W16);
  hipLaunchKernelGGL(kC_gemm, dim3(4096), dim3(256),  0, stream, R16, W16, out);
}

// Round 7
// 219.415 us; speedup vs baseline: 1.0064x; 1.0064x over previous
//
#include <hip/hip_runtime.h>

// MemoryProjection: x_t = A x_{t-1} + in_t * Bd, out = all states (2048,8,64,64) fp32.
// Chunked: out[j*64+tau] = A^(tau+1) x0_j + sum_{k<=tau} (A^(tau-k) Bd) in[j*64+k]
// => one fp16 MFMA GEMM: C[m=(j,q)][nn=(tau,n)] = R16[m][:] . W16[nn][:], K=256
//    R16 = [in(64) | x0h(64) | x0h(64) | x0l(64)], W16 = [Kmat | Ph | Pl | Ph]
// kA: P[tau]=A^(tau+1) chains via f16 h/l-compensated MFMA matmuls (1 transpose/block)
// kB: blocks 0..127 input transpose->R16; 128..191 W16 Kmat; 192..319 fused conv+scan
// kC: 128x128 MFMA GEMM, LDS-free main loop, fragments direct from L2.
//     ROUND-6 BUG: fragment buffers passed as f16x8* into lambdas -> demoted to
//     scratch (VGPR_Count=68 proved it; acc alone is 64). Now macro-expanded
//     named buffers with compile-time indices only, 3-deep rotation; LB(256,2).

typedef _Float16 f16;
typedef __attribute__((ext_vector_type(8))) _Float16 f16x8;
typedef __attribute__((ext_vector_type(4))) float f32x4;

// ---------------- kA: powers via h/l MFMA + W16 Ph/Pl + Kv + A64 ----------------
__global__ __launch_bounds__(1024) void kA_pow(
    const float* __restrict__ A, const float* __restrict__ Bm,
    float* __restrict__ A64, float* __restrict__ Kv, f16* __restrict__ W16)
{
  __shared__ __align__(16) f16 Ah[64][72],  Al[64][72];   // A row-major h/l
  __shared__ __align__(16) f16 B0h[64][72], B0l[64][72];  // ping
  __shared__ __align__(16) f16 B1h[64][72], B1l[64][72];  // pong
  __shared__ __align__(16) f16 Y8h[64][72], Y8l[64][72];  // (A^8)^T capture
  __shared__ __align__(16) f16 Ybh[64][72], Ybl[64][72];  // (A^b)^T capture

  int tau = blockIdx.x;
  int e = tau + 1;
  int a = e >> 3, b = e & 7;
  int t = threadIdx.x;
  int wave = t >> 6, lane = t & 63;
  int tn = wave >> 2, tm = wave & 3;       // 4x4 grid of 16x16 tiles
  int kg = lane >> 4, fr = lane & 15;

  // D = P * Q^T (both row-major [row][k]), h/l compensated; D split to h/l.
  auto mm = [&](f16 (*Ph)[72], f16 (*Pl)[72], f16 (*Qh)[72], f16 (*Ql)[72],
                f16 (*Dh)[72], f16 (*Dl)[72]) {
    f32x4 acc = {};
    #pragma unroll
    for (int kk = 0; kk < 2; ++kk) {
      f16x8 ah = *(const f16x8*)&Ph[tn * 16 + fr][kk * 32 + kg * 8];
      f16x8 al = *(const f16x8*)&Pl[tn * 16 + fr][kk * 32 + kg * 8];
      f16x8 bh = *(const f16x8*)&Qh[tm * 16 + fr][kk * 32 + kg * 8];
      f16x8 bl = *(const f16x8*)&Ql[tm * 16 + fr][kk * 32 + kg * 8];
      acc = __builtin_amdgcn_mfma_f32_16x16x32_f16(ah, bh, acc, 0, 0, 0);
      acc = __builtin_amdgcn_mfma_f32_16x16x32_f16(ah, bl, acc, 0, 0, 0);
      acc = __builtin_amdgcn_mfma_f32_16x16x32_f16(al, bh, acc, 0, 0, 0);
    }
    #pragma unroll
    for (int r = 0; r < 4; ++r) {
      float v = acc[r];
      f16 h = (f16)v, l = (f16)(v - (float)h);
      Dh[tn * 16 + kg * 4 + r][tm * 16 + fr] = h;
      Dl[tn * 16 + kg * 4 + r][tm * 16 + fr] = l;
    }
    __syncthreads();
  };
  auto cpy2 = [&](f16 (*Sh)[72], f16 (*Sl)[72], f16 (*Dh)[72], f16 (*Dl)[72]) {
    const unsigned* sh = (const unsigned*)Sh; unsigned* dh = (unsigned*)Dh;
    const unsigned* sl = (const unsigned*)Sl; unsigned* dl = (unsigned*)Dl;
    for (int idx = t; idx < 2304; idx += 1024) { dh[idx] = sh[idx]; dl[idx] = sl[idx]; }
  };

  // init: Ah/Al = h/l(A) row-major; ping = h/l(A^T) = Y_1
  for (int idx = t; idx < 4096; idx += 1024) {
    float v = A[idx];
    int r = idx >> 6, c2 = idx & 63;
    f16 h = (f16)v, l = (f16)(v - (float)h);
    Ah[r][c2] = h;  Al[r][c2] = l;
    B0h[c2][r] = h; B0l[c2][r] = l;
  }
  __syncthreads();

  f16 (*curH)[72] = B0h; f16 (*curL)[72] = B0l;
  f16 (*othH)[72] = B1h; f16 (*othL)[72] = B1l;
  auto swp = [&]() {
    f16 (*tH)[72] = curH; curH = othH; othH = tH;
    f16 (*tL)[72] = curL; curL = othL; othL = tL;
  };

  if (b == 1) cpy2(curH, curL, Ybh, Ybl);

  // lo chain (transposed space): Y_{i+1} = mfma(Y_i, A_rm)
  int loMax = (a >= 1) ? 8 : b;
  for (int i = 2; i <= loMax; ++i) {
    mm(curH, curL, Ah, Al, othH, othL);
    swp();
    if (i == b) cpy2(curH, curL, Ybh, Ybl);
    if (i == 8) cpy2(curH, curL, Y8h, Y8l);
  }

  f16 (*Rh)[72]; f16 (*Rl)[72]; bool tr;
  if (a == 0) {
    Rh = curH; Rl = curL; tr = true;                // result = Y_b^T
  } else {
    // H_1 = A^8 = transpose(Y_8) (Y_8 currently in cur)
    for (int idx = t; idx < 4096; idx += 1024) {
      int i = idx >> 6, j = idx & 63;
      othH[i][j] = curH[j][i];
      othL[i][j] = curL[j][i];
    }
    swp();
    __syncthreads();
    for (int a2 = 2; a2 <= a; ++a2) {               // H_{a+1} = mfma(H_a, Y8)
      mm(curH, curL, Y8h, Y8l, othH, othL);
      swp();
    }
    if (b >= 1) {                                   // P = mfma(H_a, Y_b)
      mm(curH, curL, Ybh, Ybl, othH, othL);
      swp();
    }
    Rh = curH; Rl = curL; tr = false;
  }

  // epilogue: W16 rows [64..128)=Ph, [128..192)=Pl, [192..256)=Ph; A64; Kv
  for (int idx = t; idx < 4096; idx += 1024) {
    int wn = idx >> 6, m = idx & 63;
    f16 h = tr ? Rh[m][wn] : Rh[wn][m];
    f16 l = tr ? Rl[m][wn] : Rl[wn][m];
    f16* wrow = W16 + ((size_t)(tau * 64 + wn)) * 256;
    wrow[64 + m] = h; wrow[128 + m] = l; wrow[192 + m] = h;
    if (tau == 63) A64[idx] = (float)h + (float)l;
  }
  if (t < 64) {
    float s = 0.f;
    #pragma unroll 8
    for (int m = 0; m < 64; ++m) {
      float pv = tr ? ((float)Rh[m][t] + (float)Rl[m][t])
                    : ((float)Rh[t][m] + (float)Rl[t][m]);
      s += pv * Bm[m];
    }
    if (tau < 63) Kv[(tau + 1) * 64 + t] = s;
    else          Kv[t] = Bm[t];
  }
}

// ---------------- kB: transpose | Kmat | fused conv+scan ----------------
__global__ __launch_bounds__(256) void kB_prep(
    const float* __restrict__ inp, const float* __restrict__ Kv,
    const float* __restrict__ A64,
    f16* __restrict__ R16, f16* __restrict__ W16)
{
  __shared__ __align__(16) float sm[64 * 132];
  int t = threadIdx.x;
  int b = blockIdx.x;
  if (b < 128) {
    // input transpose: R16[(j*512+q)][k] = fp16(in[j*64+k][q])
    float (*tile)[132] = (float (*)[132])sm;
    int j = b >> 2, qb = (b & 3) * 128;
    {
      int k = t >> 2, sg = (t & 3) * 32;
      const float* src = inp + j * 32768 + k * 512 + qb + sg;
      #pragma unroll
      for (int i = 0; i < 32; i += 4)
        *(f32x4*)(&tile[k][sg + i]) = *(const f32x4*)(src + i);
    }
    __syncthreads();
    int q = t >> 1, kh = (t & 1) * 32;
    f16 tmp[32];
    #pragma unroll
    for (int kk = 0; kk < 32; ++kk)
      tmp[kk] = (f16)tile[kh + kk][q];
    f16* dst = R16 + ((size_t)(j * 512 + qb + q)) * 256 + kh;
    #pragma unroll
    for (int v = 0; v < 4; ++v)
      *(f16x8*)(dst + v * 8) = *(const f16x8*)(&tmp[v * 8]);
  } else if (b < 192) {
    // Kmat rows: W16[(tau*64+wn)][k] = (k<=tau) ? Kv[tau-k][wn] : 0
    int tau = b - 128;
    float* KT = sm;
    for (int idx = t; idx < 4096; idx += 256) KT[idx] = Kv[idx];
    __syncthreads();
    int wn = t & 63, kq = t >> 6;
    f16* wrow = W16 + ((size_t)(tau * 64 + wn)) * 256 + kq * 16;
    #pragma unroll
    for (int ki = 0; ki < 16; ++ki) {
      int k = kq * 16 + ki;
      wrow[ki] = (f16)((k <= tau) ? KT[(tau - k) * 64 + wn] : 0.0f);
    }
  } else {
    // fused conv+scan: one wave per q column
    int wv = t >> 6, L = t & 63;
    int q = (b - 192) * 4 + wv;
    float ar[64], kvr[64];
    #pragma unroll
    for (int m = 0; m < 64; m += 4) {
      f32x4 v4 = *(const f32x4*)(A64 + L * 64 + m);
      ar[m] = v4.x; ar[m + 1] = v4.y; ar[m + 2] = v4.z; ar[m + 3] = v4.w;
    }
    #pragma unroll
    for (int k = 0; k < 64; ++k) kvr[k] = Kv[(63 - k) * 64 + L];
    float x = 0.f;
    float v = inp[(size_t)L * 512 + q];
    for (int j = 0; j < 32; ++j) {
      float vn = (j < 31) ? inp[(size_t)((j + 1) * 64 + L) * 512 + q] : 0.f;
      f16 hh = (f16)x, ll = (f16)(x - (float)hh);
      f16* row = R16 + ((size_t)(j * 512 + q)) * 256;
      row[64 + L] = hh; row[128 + L] = hh; row[192 + L] = ll;
      float a0 = 0.f, a1 = 0.f, c0 = 0.f, c1 = 0.f;
      #pragma unroll
      for (int m = 0; m < 64; m += 2) {
        a0 += ar[m]     * __shfl(x, m);
        a1 += ar[m + 1] * __shfl(x, m + 1);
        c0 += kvr[m]    * __shfl(v, m);
        c1 += kvr[m + 1]* __shfl(v, m + 1);
      }
      x = (a0 + a1) + (c0 + c1);
      v = vn;
    }
  }
}

// ---------------- kC: C[16384 x 4096] = R16 @ W16^T, LDS-free, reg-resident frags ----------------
#define LDg(g, av, bv)                                                          \
  {                                                                             \
    _Pragma("unroll")                                                           \
    for (int i = 0; i < 4; ++i) {                                               \
      av[i] = *(const f16x8*)(Abase + i * 16 * 256 + (g) * 32);                 \
      bv[i] = *(const f16x8*)(Bbase + i * 16 * 256 + (g) * 32);                 \
    }                                                                           \
  }
#define MMg(av, bv)                                                             \
  {                                                                             \
    _Pragma("unroll")                                                           \
    for (int mi = 0; mi < 4; ++mi)                                              \
      _Pragma("unroll")                                                         \
      for (int ni = 0; ni < 4; ++ni)                                            \
        acc[mi][ni] = __builtin_amdgcn_mfma_f32_16x16x32_f16(                   \
            av[mi], bv[ni], acc[mi][ni], 0, 0, 0);                              \
  }

__global__ __launch_bounds__(256, 2) void kC_gemm(
    const f16* __restrict__ R16, const f16* __restrict__ W16,
    float* __restrict__ out)
{
  __shared__ __align__(16) float stg[128][68];   // epilogue staging only (34.8 KB)
  int wg = blockIdx.x;
  int swz = (wg & 7) * 512 + (wg >> 3);     // XCD-contiguous mt ranges
  int mt = swz >> 5, nt = swz & 31;
  int t = threadIdx.x, wave = t >> 6, lane = t & 63;
  int wr = wave >> 1, wc = wave & 1;
  int kg = lane >> 4, fr = lane & 15;

  // fragment addresses: frag i, group g lives at base + i*16*256 + g*32
  const f16* Abase = R16 + ((size_t)(mt * 128 + wr * 64 + fr)) * 256 + kg * 8;
  const f16* Bbase = W16 + ((size_t)(nt * 128 + wc * 64 + fr)) * 256 + kg * 8;

  f32x4 acc[4][4] = {};
  f16x8 a0[4], b0[4], a1[4], b1[4], a2[4], b2[4];  // 3-deep rotation, static idx only

  LDg(0, a0, b0);
  LDg(1, a1, b1);
  LDg(2, a2, b2);
  MMg(a0, b0); LDg(3, a0, b0);
  MMg(a1, b1); LDg(4, a1, b1);
  MMg(a2, b2); LDg(5, a2, b2);
  MMg(a0, b0); LDg(6, a0, b0);
  MMg(a1, b1); LDg(7, a1, b1);
  MMg(a2, b2);
  MMg(a0, b0);
  MMg(a1, b1);

  // epilogue: per tau-half, stage 128x64 f32 tile in LDS, nt-write 32KB contiguous
  int j = mt >> 2, q0 = (mt & 3) * 128;
  #pragma unroll
  for (int half = 0; half < 2; ++half) {
    __syncthreads();
    if (wc == half) {
      #pragma unroll
      for (int mi = 0; mi < 4; ++mi)
        #pragma unroll
        for (int ni = 0; ni < 4; ++ni)
          #pragma unroll
          for (int r = 0; r < 4; ++r)
            stg[wr * 64 + mi * 16 + kg * 4 + r][ni * 16 + fr] = acc[mi][ni][r];
    }
    __syncthreads();
    int tau_g = nt * 2 + half;
    float* obase = out + (size_t)j * 2097152 + (size_t)tau_g * 32768 + (size_t)q0 * 64;
    #pragma unroll
    for (int it = 0; it < 8; ++it) {
      int fi = it * 1024 + t * 4;
      int rr = fi >> 6, cc = fi & 63;
      __builtin_nontemporal_store(*(const f32x4*)(&stg[rr][cc]),
                                  (f32x4*)(obase + fi));
    }
  }
}

extern "C" void kernel_launch(void* const* d_in, const int* in_sizes, int n_in,
                              void* d_out, int out_size, void* d_ws, size_t ws_size,
                              hipStream_t stream)
{
  (void)in_sizes; (void)n_in; (void)out_size; (void)ws_size;
  const float* inp = (const float*)d_in[0];   // (2048, 8, 64) fp32
  const float* A   = (const float*)d_in[1];   // (64, 64) fp32
  const float* Bm  = (const float*)d_in[2];   // (64, 1) fp32
  float* out = (float*)d_out;                 // (2048, 8, 64, 64) fp32

  float* ws = (float*)d_ws;
  float* A64 = ws;                            // 4096 f32   (16 KB)
  float* Kv  = ws + 4096;                     // 4096 f32   (16 KB)
  f16*  W16  = (f16*)(ws + 8192);             // 4096*256 f16 (2 MB)
  f16*  R16  = (f16*)((char*)d_ws + 2129920); // 16384*256 f16 (8 MB)

  hipLaunchKernelGGL(kA_pow,  dim3(64),   dim3(1024), 0, stream, A, Bm, A64, Kv, W16);
  hipLaunchKernelGGL(kB_prep, dim3(320),  dim3(256),  0, stream, inp, Kv, A64, R16, W16);
  hipLaunchKernelGGL(kC_gemm, dim3(4096), dim3(256),  0, stream, R16, W16, out);
}

// Round 8
// 129.602 us; speedup vs baseline: 1.7038x; 1.6930x over previous
//
#include <hip/hip_runtime.h>

// MemoryProjection: x_t = A x_{t-1} + in_t * Bd, out = all states (2048,8,64,64) fp32.
// Chunked: out[j*64+tau] = A^(tau+1) x0_j + sum_{k<=tau} (A^(tau-k) Bd) in[j*64+k]
// => one fp16 MFMA GEMM: C[m=(j,q)][nn=(tau,n)] = R16[m][:] . W16[nn][:], K=256
//    R16 = [in(64) | x0h(64) | x0h(64) | x0l(64)], W16 = [Kmat | Ph | Pl | Ph]
// kA: blocks 0..63: P[tau]=A^(tau+1) via f16 h/l MFMA chains -> W16 Ph/Pl, Kv, A64.
//     blocks 64..191: input transpose -> R16 cols [0,64) (runs on CUs idle during chains).
// kB: blocks 0..63 W16 Kmat rows; 64..191 fused conv+scan -> R16 cols [64,256).
// kC: 128x128 MFMA GEMM, BK=64 double-buffered via global_load_lds(16B) with
//     both-sides XOR swizzle (linear LDS dest + pre-swizzled global source),
//     2-phase pipeline (stage ks+1 before compute ks), nt-store staged epilogue.
//     (r6/r7 lesson: direct-from-L2 fragment loads starve MFMA at 8.6% util.)

typedef _Float16 f16;
typedef __attribute__((ext_vector_type(8))) _Float16 f16x8;
typedef __attribute__((ext_vector_type(4))) float f32x4;

// ---------------- kA: powers via h/l MFMA (+ transpose blocks) ----------------
__global__ __launch_bounds__(1024) void kA_pow(
    const float* __restrict__ A, const float* __restrict__ Bm,
    const float* __restrict__ inp,
    float* __restrict__ A64, float* __restrict__ Kv,
    f16* __restrict__ W16, f16* __restrict__ R16)
{
  __shared__ __align__(16) char sA[92160];   // 10 x 9216B, carved below
  int t = threadIdx.x;

  if (blockIdx.x >= 64) {
    // -------- transpose: one (j,qb) 64x128 tile, 1024 threads --------
    float (*tile)[132] = (float (*)[132])sA;       // 33792B, aliases chain bufs
    int bb = blockIdx.x - 64;
    int j = bb >> 2, qb = (bb & 3) * 128;
    {
      int k = t >> 4, seg = (t & 15) * 8;
      const float* src = inp + j * 32768 + k * 512 + qb + seg;
      *(f32x4*)(&tile[k][seg])     = *(const f32x4*)(src);
      *(f32x4*)(&tile[k][seg + 4]) = *(const f32x4*)(src + 4);
    }
    __syncthreads();
    {
      int q = t & 127, ks8 = (t >> 7) * 8;
      f16 tmp[8];
      #pragma unroll
      for (int kk = 0; kk < 8; ++kk)
        tmp[kk] = (f16)tile[ks8 + kk][q];
      *(f16x8*)(R16 + ((size_t)(j * 512 + qb + q)) * 256 + ks8) =
          *(const f16x8*)tmp;
    }
    return;
  }

  f16 (*Ah)[72]  = (f16 (*)[72])(sA + 0 * 9216);
  f16 (*Al)[72]  = (f16 (*)[72])(sA + 1 * 9216);
  f16 (*B0h)[72] = (f16 (*)[72])(sA + 2 * 9216);
  f16 (*B0l)[72] = (f16 (*)[72])(sA + 3 * 9216);
  f16 (*B1h)[72] = (f16 (*)[72])(sA + 4 * 9216);
  f16 (*B1l)[72] = (f16 (*)[72])(sA + 5 * 9216);
  f16 (*Y8h)[72] = (f16 (*)[72])(sA + 6 * 9216);
  f16 (*Y8l)[72] = (f16 (*)[72])(sA + 7 * 9216);
  f16 (*Ybh)[72] = (f16 (*)[72])(sA + 8 * 9216);
  f16 (*Ybl)[72] = (f16 (*)[72])(sA + 9 * 9216);

  int tau = blockIdx.x;
  int e = tau + 1;
  int a = e >> 3, b = e & 7;
  int wave = t >> 6, lane = t & 63;
  int tn = wave >> 2, tm = wave & 3;       // 4x4 grid of 16x16 tiles
  int kg = lane >> 4, fr = lane & 15;

  // D = P * Q^T (both row-major [row][k]), h/l compensated; D split to h/l.
  auto mm = [&](f16 (*Ph)[72], f16 (*Pl)[72], f16 (*Qh)[72], f16 (*Ql)[72],
                f16 (*Dh)[72], f16 (*Dl)[72]) {
    f32x4 acc = {};
    #pragma unroll
    for (int kk = 0; kk < 2; ++kk) {
      f16x8 ah = *(const f16x8*)&Ph[tn * 16 + fr][kk * 32 + kg * 8];
      f16x8 al = *(const f16x8*)&Pl[tn * 16 + fr][kk * 32 + kg * 8];
      f16x8 bh = *(const f16x8*)&Qh[tm * 16 + fr][kk * 32 + kg * 8];
      f16x8 bl = *(const f16x8*)&Ql[tm * 16 + fr][kk * 32 + kg * 8];
      acc = __builtin_amdgcn_mfma_f32_16x16x32_f16(ah, bh, acc, 0, 0, 0);
      acc = __builtin_amdgcn_mfma_f32_16x16x32_f16(ah, bl, acc, 0, 0, 0);
      acc = __builtin_amdgcn_mfma_f32_16x16x32_f16(al, bh, acc, 0, 0, 0);
    }
    #pragma unroll
    for (int r = 0; r < 4; ++r) {
      float v = acc[r];
      f16 h = (f16)v, l = (f16)(v - (float)h);
      Dh[tn * 16 + kg * 4 + r][tm * 16 + fr] = h;
      Dl[tn * 16 + kg * 4 + r][tm * 16 + fr] = l;
    }
    __syncthreads();
  };
  auto cpy2 = [&](f16 (*Sh)[72], f16 (*Sl)[72], f16 (*Dh)[72], f16 (*Dl)[72]) {
    const unsigned* sh = (const unsigned*)Sh; unsigned* dh = (unsigned*)Dh;
    const unsigned* sl = (const unsigned*)Sl; unsigned* dl = (unsigned*)Dl;
    for (int idx = t; idx < 2304; idx += 1024) { dh[idx] = sh[idx]; dl[idx] = sl[idx]; }
  };

  // init: Ah/Al = h/l(A) row-major; ping = h/l(A^T) = Y_1
  for (int idx = t; idx < 4096; idx += 1024) {
    float v = A[idx];
    int r = idx >> 6, c2 = idx & 63;
    f16 h = (f16)v, l = (f16)(v - (float)h);
    Ah[r][c2] = h;  Al[r][c2] = l;
    B0h[c2][r] = h; B0l[c2][r] = l;
  }
  __syncthreads();

  f16 (*curH)[72] = B0h; f16 (*curL)[72] = B0l;
  f16 (*othH)[72] = B1h; f16 (*othL)[72] = B1l;
  auto swp = [&]() {
    f16 (*tH)[72] = curH; curH = othH; othH = tH;
    f16 (*tL)[72] = curL; curL = othL; othL = tL;
  };

  if (b == 1) cpy2(curH, curL, Ybh, Ybl);

  // lo chain (transposed space): Y_{i+1} = mfma(Y_i, A_rm)
  int loMax = (a >= 1) ? 8 : b;
  for (int i = 2; i <= loMax; ++i) {
    mm(curH, curL, Ah, Al, othH, othL);
    swp();
    if (i == b) cpy2(curH, curL, Ybh, Ybl);
    if (i == 8) cpy2(curH, curL, Y8h, Y8l);
  }

  f16 (*Rh)[72]; f16 (*Rl)[72]; bool tr;
  if (a == 0) {
    Rh = curH; Rl = curL; tr = true;                // result = Y_b^T
  } else {
    // H_1 = A^8 = transpose(Y_8) (Y_8 currently in cur)
    for (int idx = t; idx < 4096; idx += 1024) {
      int i = idx >> 6, j = idx & 63;
      othH[i][j] = curH[j][i];
      othL[i][j] = curL[j][i];
    }
    swp();
    __syncthreads();
    for (int a2 = 2; a2 <= a; ++a2) {               // H_{a+1} = mfma(H_a, Y8)
      mm(curH, curL, Y8h, Y8l, othH, othL);
      swp();
    }
    if (b >= 1) {                                   // P = mfma(H_a, Y_b)
      mm(curH, curL, Ybh, Ybl, othH, othL);
      swp();
    }
    Rh = curH; Rl = curL; tr = false;
  }

  // epilogue: W16 rows [64..128)=Ph, [128..192)=Pl, [192..256)=Ph; A64; Kv
  for (int idx = t; idx < 4096; idx += 1024) {
    int wn = idx >> 6, m = idx & 63;
    f16 h = tr ? Rh[m][wn] : Rh[wn][m];
    f16 l = tr ? Rl[m][wn] : Rl[wn][m];
    f16* wrow = W16 + ((size_t)(tau * 64 + wn)) * 256;
    wrow[64 + m] = h; wrow[128 + m] = l; wrow[192 + m] = h;
    if (tau == 63) A64[idx] = (float)h + (float)l;
  }
  if (t < 64) {
    float s = 0.f;
    #pragma unroll 8
    for (int m = 0; m < 64; ++m) {
      float pv = tr ? ((float)Rh[m][t] + (float)Rl[m][t])
                    : ((float)Rh[t][m] + (float)Rl[t][m]);
      s += pv * Bm[m];
    }
    if (tau < 63) Kv[(tau + 1) * 64 + t] = s;
    else          Kv[t] = Bm[t];
  }
}

// ---------------- kB: Kmat rows | fused conv+scan ----------------
__global__ __launch_bounds__(256) void kB_prep(
    const float* __restrict__ inp, const float* __restrict__ Kv,
    const float* __restrict__ A64,
    f16* __restrict__ R16, f16* __restrict__ W16)
{
  __shared__ __align__(16) float sm[64 * 66];
  int t = threadIdx.x;
  int b = blockIdx.x;
  if (b < 64) {
    // Kmat rows: W16[(tau*64+wn)][k] = (k<=tau) ? Kv[tau-k][wn] : 0
    int tau = b;
    for (int idx = t; idx < 4096; idx += 256) sm[idx] = Kv[idx];
    __syncthreads();
    int wn = t & 63, kq = t >> 6;
    f16* wrow = W16 + ((size_t)(tau * 64 + wn)) * 256 + kq * 16;
    #pragma unroll
    for (int ki = 0; ki < 16; ++ki) {
      int k = kq * 16 + ki;
      wrow[ki] = (f16)((k <= tau) ? sm[(tau - k) * 64 + wn] : 0.0f);
    }
  } else {
    // fused conv+scan: one wave per q column
    int wv = t >> 6, L = t & 63;
    int q = (b - 64) * 4 + wv;
    float ar[64], kvr[64];
    #pragma unroll
    for (int m = 0; m < 64; m += 4) {
      f32x4 v4 = *(const f32x4*)(A64 + L * 64 + m);
      ar[m] = v4.x; ar[m + 1] = v4.y; ar[m + 2] = v4.z; ar[m + 3] = v4.w;
    }
    #pragma unroll
    for (int k = 0; k < 64; ++k) kvr[k] = Kv[(63 - k) * 64 + L];
    float x = 0.f;
    float v = inp[(size_t)L * 512 + q];
    for (int j = 0; j < 32; ++j) {
      float vn = (j < 31) ? inp[(size_t)((j + 1) * 64 + L) * 512 + q] : 0.f;
      f16 hh = (f16)x, ll = (f16)(x - (float)hh);
      f16* row = R16 + ((size_t)(j * 512 + q)) * 256;
      row[64 + L] = hh; row[128 + L] = hh; row[192 + L] = ll;
      float a0 = 0.f, a1 = 0.f, c0 = 0.f, c1 = 0.f;
      #pragma unroll
      for (int m = 0; m < 64; m += 2) {
        a0 += ar[m]     * __shfl(x, m);
        a1 += ar[m + 1] * __shfl(x, m + 1);
        c0 += kvr[m]    * __shfl(v, m);
        c1 += kvr[m + 1]* __shfl(v, m + 1);
      }
      x = (a0 + a1) + (c0 + c1);
      v = vn;
    }
  }
}

// ---------------- kC: C[16384 x 4096] = R16 @ W16^T ----------------
// BK=64 dbuf via global_load_lds(16B). LDS layout: linear [128 rows][64 f16],
// XOR-swizzled: LDS[row][8*c8] holds G[row][8*(c8 ^ (row&7))].
#define STAGEK(ks, dA, dB)                                                      \
  { _Pragma("unroll")                                                           \
    for (int it = 0; it < 4; ++it) {                                            \
      int rr = w32 + it * 8 + r8;                                               \
      __builtin_amdgcn_global_load_lds(                                         \
        (const __attribute__((address_space(1))) void*)                         \
          (R16 + ((size_t)(mtb + rr)) * 256 + (ks) * 64 + swc),                 \
        (__attribute__((address_space(3))) void*)((dA) + (w4 + it) * 512),      \
        16, 0, 0);                                                              \
      __builtin_amdgcn_global_load_lds(                                         \
        (const __attribute__((address_space(1))) void*)                         \
          (W16 + ((size_t)(ntb + rr)) * 256 + (ks) * 64 + swc),                 \
        (__attribute__((address_space(3))) void*)((dB) + (w4 + it) * 512),      \
        16, 0, 0);                                                              \
    } }

#define KSTEP(sA, sB)                                                           \
  { _Pragma("unroll")                                                           \
    for (int kk = 0; kk < 2; ++kk) {                                            \
      f16x8 af[4], bf[4];                                                       \
      _Pragma("unroll")                                                         \
      for (int i = 0; i < 4; ++i) {                                             \
        af[i] = *(const f16x8*)((sA) + (wr * 64 + i * 16 + fr) * 64 + colk[kk]);\
        bf[i] = *(const f16x8*)((sB) + (wc * 64 + i * 16 + fr) * 64 + colk[kk]);\
      }                                                                         \
      _Pragma("unroll")                                                         \
      for (int mi = 0; mi < 4; ++mi)                                            \
        _Pragma("unroll")                                                       \
        for (int ni = 0; ni < 4; ++ni)                                          \
          acc[mi][ni] = __builtin_amdgcn_mfma_f32_16x16x32_f16(                 \
              af[mi], bf[ni], acc[mi][ni], 0, 0, 0);                            \
    } }

#define WAITVM() asm volatile("s_waitcnt vmcnt(0)" ::: "memory")

__global__ __launch_bounds__(256, 2) void kC_gemm(
    const f16* __restrict__ R16, const f16* __restrict__ W16,
    float* __restrict__ out)
{
  __shared__ __align__(16) char smem[65536];     // 4 x 16KB staging; epilogue alias
  f16* A0 = (f16*)smem;
  f16* B0 = A0 + 8192;
  f16* A1 = B0 + 8192;
  f16* B1 = A1 + 8192;
  float (*stg)[68] = (float (*)[68])smem;        // 34816B, aliased

  int wg = blockIdx.x;
  int swz = (wg & 7) * 512 + (wg >> 3);          // XCD-contiguous mt ranges
  int mt = swz >> 5, nt = swz & 31;
  int t = threadIdx.x, w = t >> 6, lane = t & 63;
  int wr = w >> 1, wc = w & 1;
  int kg = lane >> 4, fr = lane & 15;
  int f7 = fr & 7;

  // staging indices
  int r8 = lane >> 3, c8 = lane & 7;
  int w32 = w * 32, w4 = w * 4;
  int mtb = mt * 128, ntb = nt * 128;
  int swc = 8 * (c8 ^ r8);                       // pre-swizzled source col (f16)

  // read col offsets (f16 units), swizzle-matched
  int colk[2];
  colk[0] = (kg ^ f7) * 8;
  colk[1] = ((4 + kg) ^ f7) * 8;

  f32x4 acc[4][4] = {};

  STAGEK(0, A0, B0);
  WAITVM(); __syncthreads();
  STAGEK(1, A1, B1);
  KSTEP(A0, B0);
  WAITVM(); __syncthreads();
  STAGEK(2, A0, B0);
  KSTEP(A1, B1);
  WAITVM(); __syncthreads();
  STAGEK(3, A1, B1);
  KSTEP(A0, B0);
  WAITVM(); __syncthreads();
  KSTEP(A1, B1);

  // epilogue: per tau-half, stage 128x64 f32 tile in LDS, nt-write 32KB contiguous
  int j = mt >> 2, q0 = (mt & 3) * 128;
  #pragma unroll
  for (int half = 0; half < 2; ++half) {
    __syncthreads();
    if (wc == half) {
      #pragma unroll
      for (int mi = 0; mi < 4; ++mi)
        #pragma unroll
        for (int ni = 0; ni < 4; ++ni)
          #pragma unroll
          for (int r = 0; r < 4; ++r)
            stg[wr * 64 + mi * 16 + kg * 4 + r][ni * 16 + fr] = acc[mi][ni][r];
    }
    __syncthreads();
    int tau_g = nt * 2 + half;
    float* obase = out + (size_t)j * 2097152 + (size_t)tau_g * 32768 + (size_t)q0 * 64;
    #pragma unroll
    for (int it = 0; it < 8; ++it) {
      int fi = it * 1024 + t * 4;
      int rr = fi >> 6, cc = fi & 63;
      __builtin_nontemporal_store(*(const f32x4*)(&stg[rr][cc]),
                                  (f32x4*)(obase + fi));
    }
  }
}

extern "C" void kernel_launch(void* const* d_in, const int* in_sizes, int n_in,
                              void* d_out, int out_size, void* d_ws, size_t ws_size,
                              hipStream_t stream)
{
  (void)in_sizes; (void)n_in; (void)out_size; (void)ws_size;
  const float* inp = (const float*)d_in[0];   // (2048, 8, 64) fp32
  const float* A   = (const float*)d_in[1];   // (64, 64) fp32
  const float* Bm  = (const float*)d_in[2];   // (64, 1) fp32
  float* out = (float*)d_out;                 // (2048, 8, 64, 64) fp32

  float* ws = (float*)d_ws;
  float* A64 = ws;                            // 4096 f32   (16 KB)
  float* Kv  = ws + 4096;                     // 4096 f32   (16 KB)
  f16*  W16  = (f16*)(ws + 8192);             // 4096*256 f16 (2 MB)
  f16*  R16  = (f16*)((char*)d_ws + 2129920); // 16384*256 f16 (8 MB)

  hipLaunchKernelGGL(kA_pow,  dim3(192),  dim3(1024), 0, stream, A, Bm, inp, A64, Kv, W16, R16);
  hipLaunchKernelGGL(kB_prep, dim3(192),  dim3(256),  0, stream, inp, Kv, A64, R16, W16);
  hipLaunchKernelGGL(kC_gemm, dim3(4096), dim3(256),  0, stream, R16, W16, out);
}

// Round 9
// 102.848 us; speedup vs baseline: 2.1470x; 1.2601x over previous
//
#include <hip/hip_runtime.h>

// MemoryProjection: x_t = A x_{t-1} + in_t * Bd, out = all states (2048,8,64,64) fp32.
// Chunked: out[j*64+tau] = A^(tau+1) x0_j + sum_{k<=tau} (A^(tau-k) Bd) in[j*64+k]
// => one fp16 MFMA GEMM: C[m=(j,q)][nn=(tau,n)] = R16[m][:] . W16[nn][:], K=256
//    R16 = [in(64) | x0h(64) | x0h(64) | x0l(64)], W16 = [Kmat | Ph | Pl | Ph]
// kA: blocks 0..63 power chains (h/l MFMA); 64..191 input transpose -> R16[:,0:64).
// kB: blocks 0..63 W16 Kmat; 64..191 fused conv+scan. Scan now uses LDS-broadcast
//     matvec (34 DS-ops/step) instead of __shfl (256 DS-ops/step) -- r8's ~25us cost.
// kC: 128x128 MFMA GEMM, BK=64 SINGLE-buffer staging (32KB) via global_load_lds(16B)
//     + both-sides XOR swizzle; LDS 34.8KB -> 4 blocks/CU (was 2) for cross-block
//     overlap of stage drain and MFMA; staged nt-store epilogue.

typedef _Float16 f16;
typedef __attribute__((ext_vector_type(8))) _Float16 f16x8;
typedef __attribute__((ext_vector_type(4))) float f32x4;

// ---------------- kA: powers via h/l MFMA (+ transpose blocks) ----------------
__global__ __launch_bounds__(1024) void kA_pow(
    const float* __restrict__ A, const float* __restrict__ Bm,
    const float* __restrict__ inp,
    float* __restrict__ A64, float* __restrict__ Kv,
    f16* __restrict__ W16, f16* __restrict__ R16)
{
  __shared__ __align__(16) char sA[92160];   // 10 x 9216B, carved below
  int t = threadIdx.x;

  if (blockIdx.x >= 64) {
    // -------- transpose: one (j,qb) 64x128 tile, 1024 threads --------
    float (*tile)[132] = (float (*)[132])sA;       // 33792B, aliases chain bufs
    int bb = blockIdx.x - 64;
    int j = bb >> 2, qb = (bb & 3) * 128;
    {
      int k = t >> 4, seg = (t & 15) * 8;
      const float* src = inp + j * 32768 + k * 512 + qb + seg;
      *(f32x4*)(&tile[k][seg])     = *(const f32x4*)(src);
      *(f32x4*)(&tile[k][seg + 4]) = *(const f32x4*)(src + 4);
    }
    __syncthreads();
    {
      int q = t & 127, ks8 = (t >> 7) * 8;
      f16 tmp[8];
      #pragma unroll
      for (int kk = 0; kk < 8; ++kk)
        tmp[kk] = (f16)tile[ks8 + kk][q];
      *(f16x8*)(R16 + ((size_t)(j * 512 + qb + q)) * 256 + ks8) =
          *(const f16x8*)tmp;
    }
    return;
  }

  f16 (*Ah)[72]  = (f16 (*)[72])(sA + 0 * 9216);
  f16 (*Al)[72]  = (f16 (*)[72])(sA + 1 * 9216);
  f16 (*B0h)[72] = (f16 (*)[72])(sA + 2 * 9216);
  f16 (*B0l)[72] = (f16 (*)[72])(sA + 3 * 9216);
  f16 (*B1h)[72] = (f16 (*)[72])(sA + 4 * 9216);
  f16 (*B1l)[72] = (f16 (*)[72])(sA + 5 * 9216);
  f16 (*Y8h)[72] = (f16 (*)[72])(sA + 6 * 9216);
  f16 (*Y8l)[72] = (f16 (*)[72])(sA + 7 * 9216);
  f16 (*Ybh)[72] = (f16 (*)[72])(sA + 8 * 9216);
  f16 (*Ybl)[72] = (f16 (*)[72])(sA + 9 * 9216);

  int tau = blockIdx.x;
  int e = tau + 1;
  int a = e >> 3, b = e & 7;
  int wave = t >> 6, lane = t & 63;
  int tn = wave >> 2, tm = wave & 3;       // 4x4 grid of 16x16 tiles
  int kg = lane >> 4, fr = lane & 15;

  // D = P * Q^T (both row-major [row][k]), h/l compensated; D split to h/l.
  auto mm = [&](f16 (*Ph)[72], f16 (*Pl)[72], f16 (*Qh)[72], f16 (*Ql)[72],
                f16 (*Dh)[72], f16 (*Dl)[72]) {
    f32x4 acc = {};
    #pragma unroll
    for (int kk = 0; kk < 2; ++kk) {
      f16x8 ah = *(const f16x8*)&Ph[tn * 16 + fr][kk * 32 + kg * 8];
      f16x8 al = *(const f16x8*)&Pl[tn * 16 + fr][kk * 32 + kg * 8];
      f16x8 bh = *(const f16x8*)&Qh[tm * 16 + fr][kk * 32 + kg * 8];
      f16x8 bl = *(const f16x8*)&Ql[tm * 16 + fr][kk * 32 + kg * 8];
      acc = __builtin_amdgcn_mfma_f32_16x16x32_f16(ah, bh, acc, 0, 0, 0);
      acc = __builtin_amdgcn_mfma_f32_16x16x32_f16(ah, bl, acc, 0, 0, 0);
      acc = __builtin_amdgcn_mfma_f32_16x16x32_f16(al, bh, acc, 0, 0, 0);
    }
    #pragma unroll
    for (int r = 0; r < 4; ++r) {
      float v = acc[r];
      f16 h = (f16)v, l = (f16)(v - (float)h);
      Dh[tn * 16 + kg * 4 + r][tm * 16 + fr] = h;
      Dl[tn * 16 + kg * 4 + r][tm * 16 + fr] = l;
    }
    __syncthreads();
  };
  auto cpy2 = [&](f16 (*Sh)[72], f16 (*Sl)[72], f16 (*Dh)[72], f16 (*Dl)[72]) {
    const unsigned* sh = (const unsigned*)Sh; unsigned* dh = (unsigned*)Dh;
    const unsigned* sl = (const unsigned*)Sl; unsigned* dl = (unsigned*)Dl;
    for (int idx = t; idx < 2304; idx += 1024) { dh[idx] = sh[idx]; dl[idx] = sl[idx]; }
  };

  // init: Ah/Al = h/l(A) row-major; ping = h/l(A^T) = Y_1
  for (int idx = t; idx < 4096; idx += 1024) {
    float v = A[idx];
    int r = idx >> 6, c2 = idx & 63;
    f16 h = (f16)v, l = (f16)(v - (float)h);
    Ah[r][c2] = h;  Al[r][c2] = l;
    B0h[c2][r] = h; B0l[c2][r] = l;
  }
  __syncthreads();

  f16 (*curH)[72] = B0h; f16 (*curL)[72] = B0l;
  f16 (*othH)[72] = B1h; f16 (*othL)[72] = B1l;
  auto swp = [&]() {
    f16 (*tH)[72] = curH; curH = othH; othH = tH;
    f16 (*tL)[72] = curL; curL = othL; othL = tL;
  };

  if (b == 1) cpy2(curH, curL, Ybh, Ybl);

  // lo chain (transposed space): Y_{i+1} = mfma(Y_i, A_rm)
  int loMax = (a >= 1) ? 8 : b;
  for (int i = 2; i <= loMax; ++i) {
    mm(curH, curL, Ah, Al, othH, othL);
    swp();
    if (i == b) cpy2(curH, curL, Ybh, Ybl);
    if (i == 8) cpy2(curH, curL, Y8h, Y8l);
  }

  f16 (*Rh)[72]; f16 (*Rl)[72]; bool tr;
  if (a == 0) {
    Rh = curH; Rl = curL; tr = true;                // result = Y_b^T
  } else {
    // H_1 = A^8 = transpose(Y_8) (Y_8 currently in cur)
    for (int idx = t; idx < 4096; idx += 1024) {
      int i = idx >> 6, j = idx & 63;
      othH[i][j] = curH[j][i];
      othL[i][j] = curL[j][i];
    }
    swp();
    __syncthreads();
    for (int a2 = 2; a2 <= a; ++a2) {               // H_{a+1} = mfma(H_a, Y8)
      mm(curH, curL, Y8h, Y8l, othH, othL);
      swp();
    }
    if (b >= 1) {                                   // P = mfma(H_a, Y_b)
      mm(curH, curL, Ybh, Ybl, othH, othL);
      swp();
    }
    Rh = curH; Rl = curL; tr = false;
  }

  // epilogue: W16 rows [64..128)=Ph, [128..192)=Pl, [192..256)=Ph; A64; Kv
  for (int idx = t; idx < 4096; idx += 1024) {
    int wn = idx >> 6, m = idx & 63;
    f16 h = tr ? Rh[m][wn] : Rh[wn][m];
    f16 l = tr ? Rl[m][wn] : Rl[wn][m];
    f16* wrow = W16 + ((size_t)(tau * 64 + wn)) * 256;
    wrow[64 + m] = h; wrow[128 + m] = l; wrow[192 + m] = h;
    if (tau == 63) A64[idx] = (float)h + (float)l;
  }
  if (t < 64) {
    float s = 0.f;
    #pragma unroll 8
    for (int m = 0; m < 64; ++m) {
      float pv = tr ? ((float)Rh[m][t] + (float)Rl[m][t])
                    : ((float)Rh[t][m] + (float)Rl[t][m]);
      s += pv * Bm[m];
    }
    if (tau < 63) Kv[(tau + 1) * 64 + t] = s;
    else          Kv[t] = Bm[t];
  }
}

// ---------------- kB: Kmat rows | fused conv+scan (LDS-broadcast) ----------------
__global__ __launch_bounds__(256) void kB_prep(
    const float* __restrict__ inp, const float* __restrict__ Kv,
    const float* __restrict__ A64,
    f16* __restrict__ R16, f16* __restrict__ W16)
{
  __shared__ __align__(16) float sm[64 * 66];
  int t = threadIdx.x;
  int b = blockIdx.x;
  if (b < 64) {
    // Kmat rows: W16[(tau*64+wn)][k] = (k<=tau) ? Kv[tau-k][wn] : 0
    int tau = b;
    for (int idx = t; idx < 4096; idx += 256) sm[idx] = Kv[idx];
    __syncthreads();
    int wn = t & 63, kq = t >> 6;
    f16* wrow = W16 + ((size_t)(tau * 64 + wn)) * 256 + kq * 16;
    #pragma unroll
    for (int ki = 0; ki < 16; ++ki) {
      int k = kq * 16 + ki;
      wrow[ki] = (f16)((k <= tau) ? sm[(tau - k) * 64 + wn] : 0.0f);
    }
  } else {
    // fused conv+scan: one wave per q column; x,v broadcast through LDS
    int wv = t >> 6, L = t & 63;
    int q = (b - 64) * 4 + wv;
    float* xs = sm + wv * 144;           // 64 floats, per-wave
    float* vs = xs + 72;                 // 64 floats, per-wave
    float ar[64], kvr[64];
    #pragma unroll
    for (int m = 0; m < 64; m += 4) {
      f32x4 v4 = *(const f32x4*)(A64 + L * 64 + m);
      ar[m] = v4.x; ar[m + 1] = v4.y; ar[m + 2] = v4.z; ar[m + 3] = v4.w;
    }
    #pragma unroll
    for (int k = 0; k < 64; ++k) kvr[k] = Kv[(63 - k) * 64 + L];
    float x = 0.f;
    float v = inp[(size_t)L * 512 + q];
    for (int j = 0; j < 32; ++j) {
      float vn = (j < 31) ? inp[(size_t)((j + 1) * 64 + L) * 512 + q] : 0.f;
      f16 hh = (f16)x, ll = (f16)(x - (float)hh);
      f16* row = R16 + ((size_t)(j * 512 + q)) * 256;
      row[64 + L] = hh; row[128 + L] = hh; row[192 + L] = ll;
      xs[L] = x;                          // 1 ds_write (in-order per wave)
      vs[L] = v;                          // 1 ds_write
      float a0 = 0.f, a1 = 0.f, c0 = 0.f, c1 = 0.f;
      #pragma unroll
      for (int m = 0; m < 64; m += 4) {
        f32x4 xv = *(const f32x4*)(xs + m);   // same-addr broadcast, conflict-free
        f32x4 vv = *(const f32x4*)(vs + m);
        a0 += ar[m] * xv.x + ar[m + 1] * xv.y;
        a1 += ar[m + 2] * xv.z + ar[m + 3] * xv.w;
        c0 += kvr[m] * vv.x + kvr[m + 1] * vv.y;
        c1 += kvr[m + 2] * vv.z + kvr[m + 3] * vv.w;
      }
      x = (a0 + a1) + (c0 + c1);
      v = vn;
    }
  }
}

// ---------------- kC: C[16384 x 4096] = R16 @ W16^T ----------------
// BK=64 SINGLE-buffer staging via global_load_lds(16B). LDS layout: linear
// [128 rows][64 f16], XOR-swizzled: LDS[row][8*c8] holds G[row][8*(c8^(row&7))].
#define STAGEK(ks, dA, dB)                                                      \
  { _Pragma("unroll")                                                           \
    for (int it = 0; it < 4; ++it) {                                            \
      int rr = w32 + it * 8 + r8;                                               \
      __builtin_amdgcn_global_load_lds(                                         \
        (const __attribute__((address_space(1))) void*)                         \
          (R16 + ((size_t)(mtb + rr)) * 256 + (ks) * 64 + swc),                 \
        (__attribute__((address_space(3))) void*)((dA) + (w4 + it) * 512),      \
        16, 0, 0);                                                              \
      __builtin_amdgcn_global_load_lds(                                         \
        (const __attribute__((address_space(1))) void*)                         \
          (W16 + ((size_t)(ntb + rr)) * 256 + (ks) * 64 + swc),                 \
        (__attribute__((address_space(3))) void*)((dB) + (w4 + it) * 512),      \
        16, 0, 0);                                                              \
    } }

#define KSTEP(sA, sB)                                                           \
  { _Pragma("unroll")                                                           \
    for (int kk = 0; kk < 2; ++kk) {                                            \
      f16x8 af[4], bf[4];                                                       \
      _Pragma("unroll")                                                         \
      for (int i = 0; i < 4; ++i) {                                             \
        af[i] = *(const f16x8*)((sA) + (wr * 64 + i * 16 + fr) * 64 + colk[kk]);\
        bf[i] = *(const f16x8*)((sB) + (wc * 64 + i * 16 + fr) * 64 + colk[kk]);\
      }                                                                         \
      _Pragma("unroll")                                                         \
      for (int mi = 0; mi < 4; ++mi)                                            \
        _Pragma("unroll")                                                       \
        for (int ni = 0; ni < 4; ++ni)                                          \
          acc[mi][ni] = __builtin_amdgcn_mfma_f32_16x16x32_f16(                 \
              af[mi], bf[ni], acc[mi][ni], 0, 0, 0);                            \
    } }

#define WAITVM() asm volatile("s_waitcnt vmcnt(0)" ::: "memory")

__global__ __launch_bounds__(256, 4) void kC_gemm(
    const f16* __restrict__ R16, const f16* __restrict__ W16,
    float* __restrict__ out)
{
  __shared__ __align__(16) char smem[34816];     // 32KB staging; epilogue alias
  f16* A0 = (f16*)smem;
  f16* B0 = A0 + 8192;
  float (*stg)[68] = (float (*)[68])smem;        // 34816B, aliased

  int wg = blockIdx.x;
  int swz = (wg & 7) * 512 + (wg >> 3);          // XCD-contiguous mt ranges
  int mt = swz >> 5, nt = swz & 31;
  int t = threadIdx.x, w = t >> 6, lane = t & 63;
  int wr = w >> 1, wc = w & 1;
  int kg = lane >> 4, fr = lane & 15;
  int f7 = fr & 7;

  // staging indices
  int r8 = lane >> 3, c8 = lane & 7;
  int w32 = w * 32, w4 = w * 4;
  int mtb = mt * 128, ntb = nt * 128;
  int swc = 8 * (c8 ^ r8);                       // pre-swizzled source col (f16)

  // read col offsets (f16 units), swizzle-matched
  int colk[2];
  colk[0] = (kg ^ f7) * 8;
  colk[1] = ((4 + kg) ^ f7) * 8;

  f32x4 acc[4][4] = {};

  #pragma unroll
  for (int ks = 0; ks < 4; ++ks) {
    STAGEK(ks, A0, B0);
    WAITVM();
    __syncthreads();
    KSTEP(A0, B0);
    __syncthreads();
  }

  // epilogue: per tau-half, stage 128x64 f32 tile in LDS, nt-write 32KB contiguous
  int j = mt >> 2, q0 = (mt & 3) * 128;
  #pragma unroll
  for (int half = 0; half < 2; ++half) {
    if (wc == half) {
      #pragma unroll
      for (int mi = 0; mi < 4; ++mi)
        #pragma unroll
        for (int ni = 0; ni < 4; ++ni)
          #pragma unroll
          for (int r = 0; r < 4; ++r)
            stg[wr * 64 + mi * 16 + kg * 4 + r][ni * 16 + fr] = acc[mi][ni][r];
    }
    __syncthreads();
    int tau_g = nt * 2 + half;
    float* obase = out + (size_t)j * 2097152 + (size_t)tau_g * 32768 + (size_t)q0 * 64;
    #pragma unroll
    for (int it = 0; it < 8; ++it) {
      int fi = it * 1024 + t * 4;
      int rr = fi >> 6, cc = fi & 63;
      __builtin_nontemporal_store(*(const f32x4*)(&stg[rr][cc]),
                                  (f32x4*)(obase + fi));
    }
    __syncthreads();
  }
}

extern "C" void kernel_launch(void* const* d_in, const int* in_sizes, int n_in,
                              void* d_out, int out_size, void* d_ws, size_t ws_size,
                              hipStream_t stream)
{
  (void)in_sizes; (void)n_in; (void)out_size; (void)ws_size;
  const float* inp = (const float*)d_in[0];   // (2048, 8, 64) fp32
  const float* A   = (const float*)d_in[1];   // (64, 64) fp32
  const float* Bm  = (const float*)d_in[2];   // (64, 1) fp32
  float* out = (float*)d_out;                 // (2048, 8, 64, 64) fp32

  float* ws = (float*)d_ws;
  float* A64 = ws;                            // 4096 f32   (16 KB)
  float* Kv  = ws + 4096;                     // 4096 f32   (16 KB)
  f16*  W16  = (f16*)(ws + 8192);             // 4096*256 f16 (2 MB)
  f16*  R16  = (f16*)((char*)d_ws + 2129920); // 16384*256 f16 (8 MB)

  hipLaunchKernelGGL(kA_pow,  dim3(192),  dim3(1024), 0, stream, A, Bm, inp, A64, Kv, W16, R16);
  hipLaunchKernelGGL(kB_prep, dim3(192),  dim3(256),  0, stream, inp, Kv, A64, R16, W16);
  hipLaunchKernelGGL(kC_gemm, dim3(4096), dim3(256),  0, stream, R16, W16, out);
}

// Round 10
// 100.758 us; speedup vs baseline: 2.1915x; 1.0207x over previous
//
#include <hip/hip_runtime.h>

// MemoryProjection: x_t = A x_{t-1} + in_t * Bd, out = all states (2048,8,64,64) fp32.
// Chunked: out[j*64+tau] = A^(tau+1) x0_j + sum_{k<=tau} (A^(tau-k) Bd) in[j*64+k]
// => one fp16 MFMA GEMM: C[m=(j,q)][nn=(tau,n)] = R16[m][:] . W16[nn][:], K=256
//    R16 = [in(64) | x0h(64) | x0h(64) | x0l(64)], W16 = [Kmat | Ph | Pl | Ph]
// kA: blocks 0..63 power chains (h/l MFMA); 64..191 input transpose -> R16[:,0:64).
// kB: blocks 0..63 W16 Kmat; 64..191 fused conv+scan (LDS-broadcast matvec).
// kC: 128x128 MFMA GEMM. NEW: BK=32, double-buffered (2x16KB), counted vmcnt(4)
//     pipeline with raw s_barrier (no vmcnt(0) drain per step -- T3/T4 recipe);
//     swizzle re-derived for 64B rows: src col 8*((l&3)^((l>>3)&3)), read col
//     8*(kg^((fr>>1)&3)) -> 2 lanes/bank. LDS 34.8KB -> 4 blocks/CU. nt epilogue.

typedef _Float16 f16;
typedef __attribute__((ext_vector_type(8))) _Float16 f16x8;
typedef __attribute__((ext_vector_type(4))) float f32x4;

// ---------------- kA: powers via h/l MFMA (+ transpose blocks) ----------------
__global__ __launch_bounds__(1024) void kA_pow(
    const float* __restrict__ A, const float* __restrict__ Bm,
    const float* __restrict__ inp,
    float* __restrict__ A64, float* __restrict__ Kv,
    f16* __restrict__ W16, f16* __restrict__ R16)
{
  __shared__ __align__(16) char sA[92160];   // 10 x 9216B, carved below
  int t = threadIdx.x;

  if (blockIdx.x >= 64) {
    // -------- transpose: one (j,qb) 64x128 tile, 1024 threads --------
    float (*tile)[132] = (float (*)[132])sA;       // 33792B, aliases chain bufs
    int bb = blockIdx.x - 64;
    int j = bb >> 2, qb = (bb & 3) * 128;
    {
      int k = t >> 4, seg = (t & 15) * 8;
      const float* src = inp + j * 32768 + k * 512 + qb + seg;
      *(f32x4*)(&tile[k][seg])     = *(const f32x4*)(src);
      *(f32x4*)(&tile[k][seg + 4]) = *(const f32x4*)(src + 4);
    }
    __syncthreads();
    {
      int q = t & 127, ks8 = (t >> 7) * 8;
      f16 tmp[8];
      #pragma unroll
      for (int kk = 0; kk < 8; ++kk)
        tmp[kk] = (f16)tile[ks8 + kk][q];
      *(f16x8*)(R16 + ((size_t)(j * 512 + qb + q)) * 256 + ks8) =
          *(const f16x8*)tmp;
    }
    return;
  }

  f16 (*Ah)[72]  = (f16 (*)[72])(sA + 0 * 9216);
  f16 (*Al)[72]  = (f16 (*)[72])(sA + 1 * 9216);
  f16 (*B0h)[72] = (f16 (*)[72])(sA + 2 * 9216);
  f16 (*B0l)[72] = (f16 (*)[72])(sA + 3 * 9216);
  f16 (*B1h)[72] = (f16 (*)[72])(sA + 4 * 9216);
  f16 (*B1l)[72] = (f16 (*)[72])(sA + 5 * 9216);
  f16 (*Y8h)[72] = (f16 (*)[72])(sA + 6 * 9216);
  f16 (*Y8l)[72] = (f16 (*)[72])(sA + 7 * 9216);
  f16 (*Ybh)[72] = (f16 (*)[72])(sA + 8 * 9216);
  f16 (*Ybl)[72] = (f16 (*)[72])(sA + 9 * 9216);

  int tau = blockIdx.x;
  int e = tau + 1;
  int a = e >> 3, b = e & 7;
  int wave = t >> 6, lane = t & 63;
  int tn = wave >> 2, tm = wave & 3;       // 4x4 grid of 16x16 tiles
  int kg = lane >> 4, fr = lane & 15;

  // D = P * Q^T (both row-major [row][k]), h/l compensated; D split to h/l.
  auto mm = [&](f16 (*Ph)[72], f16 (*Pl)[72], f16 (*Qh)[72], f16 (*Ql)[72],
                f16 (*Dh)[72], f16 (*Dl)[72]) {
    f32x4 acc = {};
    #pragma unroll
    for (int kk = 0; kk < 2; ++kk) {
      f16x8 ah = *(const f16x8*)&Ph[tn * 16 + fr][kk * 32 + kg * 8];
      f16x8 al = *(const f16x8*)&Pl[tn * 16 + fr][kk * 32 + kg * 8];
      f16x8 bh = *(const f16x8*)&Qh[tm * 16 + fr][kk * 32 + kg * 8];
      f16x8 bl = *(const f16x8*)&Ql[tm * 16 + fr][kk * 32 + kg * 8];
      acc = __builtin_amdgcn_mfma_f32_16x16x32_f16(ah, bh, acc, 0, 0, 0);
      acc = __builtin_amdgcn_mfma_f32_16x16x32_f16(ah, bl, acc, 0, 0, 0);
      acc = __builtin_amdgcn_mfma_f32_16x16x32_f16(al, bh, acc, 0, 0, 0);
    }
    #pragma unroll
    for (int r = 0; r < 4; ++r) {
      float v = acc[r];
      f16 h = (f16)v, l = (f16)(v - (float)h);
      Dh[tn * 16 + kg * 4 + r][tm * 16 + fr] = h;
      Dl[tn * 16 + kg * 4 + r][tm * 16 + fr] = l;
    }
    __syncthreads();
  };
  auto cpy2 = [&](f16 (*Sh)[72], f16 (*Sl)[72], f16 (*Dh)[72], f16 (*Dl)[72]) {
    const unsigned* sh = (const unsigned*)Sh; unsigned* dh = (unsigned*)Dh;
    const unsigned* sl = (const unsigned*)Sl; unsigned* dl = (unsigned*)Dl;
    for (int idx = t; idx < 2304; idx += 1024) { dh[idx] = sh[idx]; dl[idx] = sl[idx]; }
  };

  // init: Ah/Al = h/l(A) row-major; ping = h/l(A^T) = Y_1
  for (int idx = t; idx < 4096; idx += 1024) {
    float v = A[idx];
    int r = idx >> 6, c2 = idx & 63;
    f16 h = (f16)v, l = (f16)(v - (float)h);
    Ah[r][c2] = h;  Al[r][c2] = l;
    B0h[c2][r] = h; B0l[c2][r] = l;
  }
  __syncthreads();

  f16 (*curH)[72] = B0h; f16 (*curL)[72] = B0l;
  f16 (*othH)[72] = B1h; f16 (*othL)[72] = B1l;
  auto swp = [&]() {
    f16 (*tH)[72] = curH; curH = othH; othH = tH;
    f16 (*tL)[72] = curL; curL = othL; othL = tL;
  };

  if (b == 1) cpy2(curH, curL, Ybh, Ybl);

  // lo chain (transposed space): Y_{i+1} = mfma(Y_i, A_rm)
  int loMax = (a >= 1) ? 8 : b;
  for (int i = 2; i <= loMax; ++i) {
    mm(curH, curL, Ah, Al, othH, othL);
    swp();
    if (i == b) cpy2(curH, curL, Ybh, Ybl);
    if (i == 8) cpy2(curH, curL, Y8h, Y8l);
  }

  f16 (*Rh)[72]; f16 (*Rl)[72]; bool tr;
  if (a == 0) {
    Rh = curH; Rl = curL; tr = true;                // result = Y_b^T
  } else {
    // H_1 = A^8 = transpose(Y_8) (Y_8 currently in cur)
    for (int idx = t; idx < 4096; idx += 1024) {
      int i = idx >> 6, j = idx & 63;
      othH[i][j] = curH[j][i];
      othL[i][j] = curL[j][i];
    }
    swp();
    __syncthreads();
    for (int a2 = 2; a2 <= a; ++a2) {               // H_{a+1} = mfma(H_a, Y8)
      mm(curH, curL, Y8h, Y8l, othH, othL);
      swp();
    }
    if (b >= 1) {                                   // P = mfma(H_a, Y_b)
      mm(curH, curL, Ybh, Ybl, othH, othL);
      swp();
    }
    Rh = curH; Rl = curL; tr = false;
  }

  // epilogue: W16 rows [64..128)=Ph, [128..192)=Pl, [192..256)=Ph; A64; Kv
  for (int idx = t; idx < 4096; idx += 1024) {
    int wn = idx >> 6, m = idx & 63;
    f16 h = tr ? Rh[m][wn] : Rh[wn][m];
    f16 l = tr ? Rl[m][wn] : Rl[wn][m];
    f16* wrow = W16 + ((size_t)(tau * 64 + wn)) * 256;
    wrow[64 + m] = h; wrow[128 + m] = l; wrow[192 + m] = h;
    if (tau == 63) A64[idx] = (float)h + (float)l;
  }
  if (t < 64) {
    float s = 0.f;
    #pragma unroll 8
    for (int m = 0; m < 64; ++m) {
      float pv = tr ? ((float)Rh[m][t] + (float)Rl[m][t])
                    : ((float)Rh[t][m] + (float)Rl[t][m]);
      s += pv * Bm[m];
    }
    if (tau < 63) Kv[(tau + 1) * 64 + t] = s;
    else          Kv[t] = Bm[t];
  }
}

// ---------------- kB: Kmat rows | fused conv+scan (LDS-broadcast) ----------------
__global__ __launch_bounds__(256) void kB_prep(
    const float* __restrict__ inp, const float* __restrict__ Kv,
    const float* __restrict__ A64,
    f16* __restrict__ R16, f16* __restrict__ W16)
{
  __shared__ __align__(16) float sm[64 * 66];
  int t = threadIdx.x;
  int b = blockIdx.x;
  if (b < 64) {
    // Kmat rows: W16[(tau*64+wn)][k] = (k<=tau) ? Kv[tau-k][wn] : 0
    int tau = b;
    for (int idx = t; idx < 4096; idx += 256) sm[idx] = Kv[idx];
    __syncthreads();
    int wn = t & 63, kq = t >> 6;
    f16* wrow = W16 + ((size_t)(tau * 64 + wn)) * 256 + kq * 16;
    #pragma unroll
    for (int ki = 0; ki < 16; ++ki) {
      int k = kq * 16 + ki;
      wrow[ki] = (f16)((k <= tau) ? sm[(tau - k) * 64 + wn] : 0.0f);
    }
  } else {
    // fused conv+scan: one wave per q column; x,v broadcast through LDS
    int wv = t >> 6, L = t & 63;
    int q = (b - 64) * 4 + wv;
    float* xs = sm + wv * 144;           // 64 floats, per-wave
    float* vs = xs + 72;                 // 64 floats, per-wave
    float ar[64], kvr[64];
    #pragma unroll
    for (int m = 0; m < 64; m += 4) {
      f32x4 v4 = *(const f32x4*)(A64 + L * 64 + m);
      ar[m] = v4.x; ar[m + 1] = v4.y; ar[m + 2] = v4.z; ar[m + 3] = v4.w;
    }
    #pragma unroll
    for (int k = 0; k < 64; ++k) kvr[k] = Kv[(63 - k) * 64 + L];
    float x = 0.f;
    float v = inp[(size_t)L * 512 + q];
    for (int j = 0; j < 32; ++j) {
      float vn = (j < 31) ? inp[(size_t)((j + 1) * 64 + L) * 512 + q] : 0.f;
      f16 hh = (f16)x, ll = (f16)(x - (float)hh);
      f16* row = R16 + ((size_t)(j * 512 + q)) * 256;
      row[64 + L] = hh; row[128 + L] = hh; row[192 + L] = ll;
      xs[L] = x;                          // 1 ds_write (in-order per wave)
      vs[L] = v;                          // 1 ds_write
      float a0 = 0.f, a1 = 0.f, c0 = 0.f, c1 = 0.f;
      #pragma unroll
      for (int m = 0; m < 64; m += 4) {
        f32x4 xv = *(const f32x4*)(xs + m);   // same-addr broadcast, conflict-free
        f32x4 vv = *(const f32x4*)(vs + m);
        a0 += ar[m] * xv.x + ar[m + 1] * xv.y;
        a1 += ar[m + 2] * xv.z + ar[m + 3] * xv.w;
        c0 += kvr[m] * vv.x + kvr[m + 1] * vv.y;
        c1 += kvr[m + 2] * vv.z + kvr[m + 3] * vv.w;
      }
      x = (a0 + a1) + (c0 + c1);
      v = vn;
    }
  }
}

// ---------------- kC: C[16384 x 4096] = R16 @ W16^T ----------------
// BK=32, 2 buffers (16KB each: A 8KB + B 8KB), counted vmcnt(4), raw barriers.
// LDS rows 64B: LDS[row][slot] holds G[row][slot ^ ((row>>1)&3)] (slot = 8 f16).
#define STAGE32(ks, dbuf)                                                       \
  { _Pragma("unroll")                                                           \
    for (int it = 0; it < 2; ++it) {                                            \
      __builtin_amdgcn_global_load_lds(                                         \
        (const __attribute__((address_space(1))) void*)                         \
          (R16 + ((size_t)(mtb + w32 + it * 16 + l4)) * 256 + (ks) * 32 + swc32),\
        (__attribute__((address_space(3))) void*)((dbuf) + w * 1024 + it * 512),\
        16, 0, 0);                                                              \
      __builtin_amdgcn_global_load_lds(                                         \
        (const __attribute__((address_space(1))) void*)                         \
          (W16 + ((size_t)(ntb + w32 + it * 16 + l4)) * 256 + (ks) * 32 + swc32),\
        (__attribute__((address_space(3))) void*)((dbuf) + 4096 + w * 1024 + it * 512),\
        16, 0, 0);                                                              \
    } }

#define KSTEP32(sbuf)                                                           \
  { f16x8 af[4], bf[4];                                                         \
    _Pragma("unroll")                                                           \
    for (int i = 0; i < 4; ++i) {                                               \
      af[i] = *(const f16x8*)((sbuf) + (wr * 64 + i * 16 + fr) * 32 + scol);    \
      bf[i] = *(const f16x8*)((sbuf) + 4096 + (wc * 64 + i * 16 + fr) * 32 + scol);\
    }                                                                           \
    _Pragma("unroll")                                                           \
    for (int mi = 0; mi < 4; ++mi)                                              \
      _Pragma("unroll")                                                         \
      for (int ni = 0; ni < 4; ++ni)                                            \
        acc[mi][ni] = __builtin_amdgcn_mfma_f32_16x16x32_f16(                   \
            af[mi], bf[ni], acc[mi][ni], 0, 0, 0);                              \
  }

#define WAITN(n) asm volatile("s_waitcnt vmcnt(" #n ")" ::: "memory")
#define BAR()                                                                   \
  { __builtin_amdgcn_sched_barrier(0); __builtin_amdgcn_s_barrier();            \
    __builtin_amdgcn_sched_barrier(0); }

__global__ __launch_bounds__(256, 4) void kC_gemm(
    const f16* __restrict__ R16, const f16* __restrict__ W16,
    float* __restrict__ out)
{
  __shared__ __align__(16) char smem[34816];     // 2x16KB staging; epilogue alias
  f16* b0v = (f16*)smem;
  f16* b1v = b0v + 8192;
  float (*stg)[68] = (float (*)[68])smem;        // 34816B, aliased

  int wg = blockIdx.x;
  int swz = (wg & 7) * 512 + (wg >> 3);          // XCD-contiguous mt ranges
  int mt = swz >> 5, nt = swz & 31;
  int t = threadIdx.x, w = t >> 6, lane = t & 63;
  int wr = w >> 1, wc = w & 1;
  int kg = lane >> 4, fr = lane & 15;

  // staging indices (BK=32, 64B rows, 4 lanes/row)
  int l4 = lane >> 2;
  int swc32 = 8 * ((lane & 3) ^ ((lane >> 3) & 3));   // pre-swizzled src col (f16)
  int w32 = w * 32;
  int mtb = mt * 128, ntb = nt * 128;
  int scol = 8 * (kg ^ ((fr >> 1) & 3));              // swizzle-matched read col

  f32x4 acc[4][4] = {};

  STAGE32(0, b0v);
  STAGE32(1, b1v); WAITN(4); BAR(); KSTEP32(b0v); BAR();
  STAGE32(2, b0v); WAITN(4); BAR(); KSTEP32(b1v); BAR();
  STAGE32(3, b1v); WAITN(4); BAR(); KSTEP32(b0v); BAR();
  STAGE32(4, b0v); WAITN(4); BAR(); KSTEP32(b1v); BAR();
  STAGE32(5, b1v); WAITN(4); BAR(); KSTEP32(b0v); BAR();
  STAGE32(6, b0v); WAITN(4); BAR(); KSTEP32(b1v); BAR();
  STAGE32(7, b1v); WAITN(4); BAR(); KSTEP32(b0v); BAR();
  WAITN(0); BAR(); KSTEP32(b1v); BAR();

  // epilogue: per tau-half, stage 128x64 f32 tile in LDS, nt-write 32KB contiguous
  int j = mt >> 2, q0 = (mt & 3) * 128;
  #pragma unroll
  for (int half = 0; half < 2; ++half) {
    if (wc == half) {
      #pragma unroll
      for (int mi = 0; mi < 4; ++mi)
        #pragma unroll
        for (int ni = 0; ni < 4; ++ni)
          #pragma unroll
          for (int r = 0; r < 4; ++r)
            stg[wr * 64 + mi * 16 + kg * 4 + r][ni * 16 + fr] = acc[mi][ni][r];
    }
    asm volatile("s_waitcnt lgkmcnt(0)" ::: "memory");
    BAR();
    int tau_g = nt * 2 + half;
    float* obase = out + (size_t)j * 2097152 + (size_t)tau_g * 32768 + (size_t)q0 * 64;
    #pragma unroll
    for (int it = 0; it < 8; ++it) {
      int fi = it * 1024 + t * 4;
      int rr = fi >> 6, cc = fi & 63;
      __builtin_nontemporal_store(*(const f32x4*)(&stg[rr][cc]),
                                  (f32x4*)(obase + fi));
    }
    BAR();
  }
}

extern "C" void kernel_launch(void* const* d_in, const int* in_sizes, int n_in,
                              void* d_out, int out_size, void* d_ws, size_t ws_size,
                              hipStream_t stream)
{
  (void)in_sizes; (void)n_in; (void)out_size; (void)ws_size;
  const float* inp = (const float*)d_in[0];   // (2048, 8, 64) fp32
  const float* A   = (const float*)d_in[1];   // (64, 64) fp32
  const float* Bm  = (const float*)d_in[2];   // (64, 1) fp32
  float* out = (float*)d_out;                 // (2048, 8, 64, 64) fp32

  float* ws = (float*)d_ws;
  float* A64 = ws;                            // 4096 f32   (16 KB)
  float* Kv  = ws + 4096;                     // 4096 f32   (16 KB)
  f16*  W16  = (f16*)(ws + 8192);             // 4096*256 f16 (2 MB)
  f16*  R16  = (f16*)((char*)d_ws + 2129920); // 16384*256 f16 (8 MB)

  hipLaunchKernelGGL(kA_pow,  dim3(192),  dim3(1024), 0, stream, A, Bm, inp, A64, Kv, W16, R16);
  hipLaunchKernelGGL(kB_prep, dim3(192),  dim3(256),  0, stream, inp, Kv, A64, R16, W16);
  hipLaunchKernelGGL(kC_gemm, dim3(4096), dim3(256),  0, stream, R16, W16, out);
}